// Round 1
// baseline (899.578 us; speedup 1.0000x reference)
//
#include <hip/hip_runtime.h>
#include <cstdint>
#include <cstddef>

typedef unsigned short u16;
typedef unsigned int u32;
typedef short bf16x8 __attribute__((ext_vector_type(8)));
typedef float f32x4 __attribute__((ext_vector_type(4)));
typedef u16 u16x4 __attribute__((ext_vector_type(4)));

__device__ __forceinline__ u16 f2bf(float f) {
  u32 u = __float_as_uint(f);
  return (u16)((u + 0x7FFFu + ((u >> 16) & 1u)) >> 16);
}
__device__ __forceinline__ float bf2f(u16 h) {
  return __uint_as_float(((u32)h) << 16);
}

__device__ __forceinline__ void gload_lds16(const void* g, void* l) {
  __builtin_amdgcn_global_load_lds((const __attribute__((address_space(1))) u32*)g,
                                   (__attribute__((address_space(3))) u32*)l, 16, 0, 0);
}

// ---------------- weight cast fp32 -> bf16 ----------------
__global__ __launch_bounds__(256) void castw(const float* __restrict__ src,
                                             u16* __restrict__ dst, int n4) {
  int i = blockIdx.x * 256 + threadIdx.x;
  if (i < n4) {
    float4 v = ((const float4*)src)[i];
    u16x4 r;
    r.x = f2bf(v.x); r.y = f2bf(v.y); r.z = f2bf(v.z); r.w = f2bf(v.w);
    ((u16x4*)dst)[i] = r;
  }
}

// ---------------- RMSNorm: fp32 [rows,1024] -> bf16 ----------------
__global__ __launch_bounds__(256) void rmsnorm_k(const float* __restrict__ x,
                                                 const float* __restrict__ gamma,
                                                 u16* __restrict__ o) {
  const int row = blockIdx.x;
  const int t = threadIdx.x;
  float4 v = ((const float4*)(x + (size_t)row * 1024))[t];
  float ss = v.x * v.x + v.y * v.y + v.z * v.z + v.w * v.w;
  #pragma unroll
  for (int m = 1; m < 64; m <<= 1) ss += __shfl_xor(ss, m);
  __shared__ float wsum[4];
  if ((t & 63) == 0) wsum[t >> 6] = ss;
  __syncthreads();
  float tot = wsum[0] + wsum[1] + wsum[2] + wsum[3];
  float inv = rsqrtf(tot * (1.0f / 1024.0f) + 1e-5f);
  float4 g = ((const float4*)gamma)[t];
  u16x4 r;
  r.x = f2bf(v.x * inv * g.x);
  r.y = f2bf(v.y * inv * g.y);
  r.z = f2bf(v.z * inv * g.z);
  r.w = f2bf(v.w * inv * g.w);
  ((u16x4*)(o + (size_t)row * 1024))[t] = r;
}

// ---------------- GEMM: C[M,N] = A[M,K] * B[N,K]^T (bf16 in, fp32 acc) ----
// EPI 0: out bf16 = acc*scale
// EPI 1: out fp32 = acc + ep_fp32[idx]
// EPI 2: out bf16 = silu(ep_bf16[idx]) * acc     (SwiGLU: ep = gate)
template <int EPI>
__global__ __launch_bounds__(256, 2)
void gemm_bt(const u16* __restrict__ A, const u16* __restrict__ B,
             void* out, const void* ep, int M, int N, int K, float scale) {
  __shared__ u16 As[128 * 32];
  __shared__ u16 Bs[128 * 32];
  const int tid = threadIdx.x;
  const int lane = tid & 63;
  const int w = tid >> 6;
  const int wr = w >> 1, wc = w & 1;
  const int m0 = blockIdx.y * 128;
  const int n0 = blockIdx.x * 128;
  const int lr = lane & 15;
  const int lk = lane >> 4;
  const int srow = lane >> 2;        // 0..15 rows per staging call
  const int scol = (lane & 3) * 8;   // 8-elem (16B) column chunk

  const f32x4 zero4 = {0.f, 0.f, 0.f, 0.f};
  f32x4 acc[4][4];
  #pragma unroll
  for (int i = 0; i < 4; i++)
    #pragma unroll
    for (int j = 0; j < 4; j++) acc[i][j] = zero4;

  for (int kt = 0; kt < K; kt += 32) {
    __syncthreads();
    #pragma unroll
    for (int c = 0; c < 2; c++) {
      const int rbase = w * 32 + c * 16;
      gload_lds16(A + (size_t)(m0 + rbase + srow) * K + kt + scol, &As[rbase * 32]);
      gload_lds16(B + (size_t)(n0 + rbase + srow) * K + kt + scol, &Bs[rbase * 32]);
    }
    __syncthreads();
    bf16x8 af[4], bfr[4];
    #pragma unroll
    for (int i = 0; i < 4; i++)
      af[i] = *(const bf16x8*)&As[(wr * 64 + i * 16 + lr) * 32 + lk * 8];
    #pragma unroll
    for (int j = 0; j < 4; j++)
      bfr[j] = *(const bf16x8*)&Bs[(wc * 64 + j * 16 + lr) * 32 + lk * 8];
    #pragma unroll
    for (int i = 0; i < 4; i++)
      #pragma unroll
      for (int j = 0; j < 4; j++)
        acc[i][j] = __builtin_amdgcn_mfma_f32_16x16x32_bf16(af[i], bfr[j], acc[i][j], 0, 0, 0);
  }

  const int r0 = lk * 4;
  #pragma unroll
  for (int i = 0; i < 4; i++) {
    #pragma unroll
    for (int j = 0; j < 4; j++) {
      #pragma unroll
      for (int r = 0; r < 4; r++) {
        const int grow = m0 + wr * 64 + i * 16 + r0 + r;
        const int gcol = n0 + wc * 64 + j * 16 + lr;
        const size_t idx = (size_t)grow * N + gcol;
        const float val = acc[i][j][r];
        if (EPI == 0) {
          ((u16*)out)[idx] = f2bf(val * scale);
        } else if (EPI == 1) {
          ((float*)out)[idx] = ((const float*)ep)[idx] + val;
        } else {
          float gv = bf2f(((const u16*)ep)[idx]);
          float sg = gv / (1.f + __expf(-gv));
          ((u16*)out)[idx] = f2bf(sg * val);
        }
      }
    }
  }
}

// ---------------- causal flash attention ----------------
// q,k,v,o: bf16 [B*S, H*64] = [8192, 1024]; q pre-scaled by 1/8.
// grid: (qtile=32, bh=64), block 256 (4 waves); wave handles 16 q-rows.
__global__ __launch_bounds__(256, 2)
void attn_fwd(const u16* __restrict__ q, const u16* __restrict__ k,
              const u16* __restrict__ v, u16* __restrict__ o) {
  __shared__ u16 Ks[32 * 72];      // [key][d], pad to 72
  __shared__ u16 Vs[64 * 40];      // [d][key], pad to 40
  __shared__ u16 Ps[4][16 * 40];   // per-wave P [qrow][key], pad to 40
  const int tid = threadIdx.x, lane = tid & 63, w = tid >> 6;
  const int bh = blockIdx.y, b = bh >> 4, h = bh & 15;
  const int qbase = blockIdx.x * 64;
  const size_t base = ((size_t)b * 2048) * 1024 + (size_t)h * 64;
  const int lr = lane & 15, lk = lane >> 4;
  const int r0 = lk * 4;

  // Q fragments (stay in registers): wave w rows qbase + w*16 + lr
  const int qrow_f = qbase + w * 16 + lr;
  bf16x8 qf[2];
  #pragma unroll
  for (int kk = 0; kk < 2; kk++)
    qf[kk] = *(const bf16x8*)&q[base + (size_t)qrow_f * 1024 + kk * 32 + lk * 8];

  const f32x4 zero4 = {0.f, 0.f, 0.f, 0.f};
  f32x4 accO[4];
  #pragma unroll
  for (int fd = 0; fd < 4; fd++) accO[fd] = zero4;
  float mrow[4], lrow[4];
  #pragma unroll
  for (int r = 0; r < 4; r++) { mrow[r] = -1e30f; lrow[r] = 0.f; }

  const int skey = tid >> 3;        // 0..31
  const int sd = (tid & 7) * 8;     // 0..56
  const int nkb = blockIdx.x * 2 + 2;

  for (int kb = 0; kb < nkb; kb++) {
    const int kbase = kb * 32;
    __syncthreads();
    {
      bf16x8 kv = *(const bf16x8*)&k[base + (size_t)(kbase + skey) * 1024 + sd];
      *(bf16x8*)&Ks[skey * 72 + sd] = kv;
      bf16x8 vv = *(const bf16x8*)&v[base + (size_t)(kbase + skey) * 1024 + sd];
      #pragma unroll
      for (int j = 0; j < 8; j++) Vs[(sd + j) * 40 + skey] = (u16)vv[j];
    }
    __syncthreads();

    // S = Q K^T   (per wave: 16 q-rows x 32 keys)
    f32x4 s[2] = {zero4, zero4};
    #pragma unroll
    for (int fn = 0; fn < 2; fn++)
      #pragma unroll
      for (int kk = 0; kk < 2; kk++) {
        bf16x8 kf = *(const bf16x8*)&Ks[(fn * 16 + lr) * 72 + kk * 32 + lk * 8];
        s[fn] = __builtin_amdgcn_mfma_f32_16x16x32_bf16(qf[kk], kf, s[fn], 0, 0, 0);
      }

    // causal mask
    #pragma unroll
    for (int fn = 0; fn < 2; fn++)
      #pragma unroll
      for (int r = 0; r < 4; r++) {
        const int qr = qbase + w * 16 + r0 + r;
        const int ky = kbase + fn * 16 + lr;
        if (ky > qr) s[fn][r] = -1e30f;
      }

    // online softmax per q-row (row spread over 16-lane group)
    #pragma unroll
    for (int r = 0; r < 4; r++) {
      float mx = fmaxf(s[0][r], s[1][r]);
      #pragma unroll
      for (int m = 1; m < 16; m <<= 1) mx = fmaxf(mx, __shfl_xor(mx, m));
      const float mnew = fmaxf(mrow[r], mx);
      const float alpha = __expf(mrow[r] - mnew);
      const float p0 = __expf(s[0][r] - mnew);
      const float p1 = __expf(s[1][r] - mnew);
      float rs = p0 + p1;
      #pragma unroll
      for (int m = 1; m < 16; m <<= 1) rs += __shfl_xor(rs, m);
      lrow[r] = lrow[r] * alpha + rs;
      mrow[r] = mnew;
      #pragma unroll
      for (int fd = 0; fd < 4; fd++) accO[fd][r] *= alpha;
      Ps[w][(r0 + r) * 40 + lr] = f2bf(p0);
      Ps[w][(r0 + r) * 40 + 16 + lr] = f2bf(p1);
    }
    __syncthreads();

    // O += P V
    bf16x8 pf = *(const bf16x8*)&Ps[w][lr * 40 + lk * 8];
    #pragma unroll
    for (int fd = 0; fd < 4; fd++) {
      bf16x8 vf = *(const bf16x8*)&Vs[(fd * 16 + lr) * 40 + lk * 8];
      accO[fd] = __builtin_amdgcn_mfma_f32_16x16x32_bf16(pf, vf, accO[fd], 0, 0, 0);
    }
  }

  #pragma unroll
  for (int fd = 0; fd < 4; fd++)
    #pragma unroll
    for (int r = 0; r < 4; r++) {
      const int qr = qbase + w * 16 + r0 + r;
      o[base + (size_t)qr * 1024 + fd * 16 + lr] = f2bf(accO[fd][r] / lrow[r]);
    }
}

// ---------------- host ----------------
extern "C" void kernel_launch(void* const* d_in, const int* in_sizes, int n_in,
                              void* d_out, int out_size, void* d_ws, size_t ws_size,
                              hipStream_t stream) {
  const float* x      = (const float*)d_in[0];
  const float* W_q    = (const float*)d_in[1];
  const float* W_k    = (const float*)d_in[2];
  const float* W_v    = (const float*)d_in[3];
  const float* W_o    = (const float*)d_in[4];
  const float* gamma1 = (const float*)d_in[5];
  const float* gamma2 = (const float*)d_in[6];
  const float* W1     = (const float*)d_in[7];
  const float* W2     = (const float*)d_in[8];
  const float* W3     = (const float*)d_in[9];

  char* ws = (char*)d_ws;
  const size_t MB = 1ull << 20;
  u16* Wq_b  = (u16*)(ws + 0 * MB);
  u16* Wk_b  = (u16*)(ws + 2 * MB);
  u16* Wv_b  = (u16*)(ws + 4 * MB);
  u16* Wo_b  = (u16*)(ws + 6 * MB);
  u16* W1_b  = (u16*)(ws + 8 * MB);
  u16* W3_b  = (u16*)(ws + 16 * MB);
  u16* W2_b  = (u16*)(ws + 24 * MB);
  u16* xn    = (u16*)(ws + 32 * MB);   // 16 MB, reused for both norms
  u16* qb    = (u16*)(ws + 48 * MB);
  u16* kb    = (u16*)(ws + 64 * MB);
  u16* vb    = (u16*)(ws + 80 * MB);
  u16* attnb = (u16*)(ws + 96 * MB);
  u16* gbuf  = (u16*)(ws + 112 * MB);  // 64 MB -> ends at 176 MB
  u16* hbuf  = (u16*)(ws + 48 * MB);   // reuse q/k/v/attn region (64 MB)
  float* x1  = (float*)d_out;          // fp32 residual lives in d_out

  // weight casts
  castw<<<1024, 256, 0, stream>>>(W_q, Wq_b, 262144);
  castw<<<1024, 256, 0, stream>>>(W_k, Wk_b, 262144);
  castw<<<1024, 256, 0, stream>>>(W_v, Wv_b, 262144);
  castw<<<1024, 256, 0, stream>>>(W_o, Wo_b, 262144);
  castw<<<4096, 256, 0, stream>>>(W1, W1_b, 1048576);
  castw<<<4096, 256, 0, stream>>>(W3, W3_b, 1048576);
  castw<<<4096, 256, 0, stream>>>(W2, W2_b, 1048576);

  // attention half
  rmsnorm_k<<<8192, 256, 0, stream>>>(x, gamma1, xn);
  gemm_bt<0><<<dim3(8, 64), 256, 0, stream>>>(xn, Wq_b, qb, nullptr, 8192, 1024, 1024, 0.125f);
  gemm_bt<0><<<dim3(8, 64), 256, 0, stream>>>(xn, Wk_b, kb, nullptr, 8192, 1024, 1024, 1.0f);
  gemm_bt<0><<<dim3(8, 64), 256, 0, stream>>>(xn, Wv_b, vb, nullptr, 8192, 1024, 1024, 1.0f);
  attn_fwd<<<dim3(32, 64), 256, 0, stream>>>(qb, kb, vb, attnb);
  gemm_bt<1><<<dim3(8, 64), 256, 0, stream>>>(attnb, Wo_b, x1, x, 8192, 1024, 1024, 1.0f);

  // FFN half
  rmsnorm_k<<<8192, 256, 0, stream>>>(x1, gamma2, xn);
  gemm_bt<0><<<dim3(32, 64), 256, 0, stream>>>(xn, W1_b, gbuf, nullptr, 8192, 4096, 1024, 1.0f);
  gemm_bt<2><<<dim3(32, 64), 256, 0, stream>>>(xn, W3_b, hbuf, gbuf, 8192, 4096, 1024, 1.0f);
  gemm_bt<1><<<dim3(8, 64), 256, 0, stream>>>(hbuf, W2_b, (float*)d_out, x1, 8192, 1024, 4096, 1.0f);
}

// Round 2
// 579.392 us; speedup vs baseline: 1.5526x; 1.5526x over previous
//
#include <hip/hip_runtime.h>
#include <cstdint>
#include <cstddef>

typedef unsigned short u16;
typedef unsigned int u32;
typedef short bf16x8 __attribute__((ext_vector_type(8)));
typedef float f32x4 __attribute__((ext_vector_type(4)));
typedef float f32x16 __attribute__((ext_vector_type(16)));
typedef u16 u16x4 __attribute__((ext_vector_type(4)));

__device__ __forceinline__ u16 f2bf(float f) {
  u32 u = __float_as_uint(f);
  return (u16)((u + 0x7FFFu + ((u >> 16) & 1u)) >> 16);
}
__device__ __forceinline__ float bf2f(u16 h) {
  return __uint_as_float(((u32)h) << 16);
}
__device__ __forceinline__ u32 pack2(float a, float b) {
  return (u32)f2bf(a) | ((u32)f2bf(b) << 16);
}

__device__ __forceinline__ void gload_lds16(const void* g, void* l) {
  __builtin_amdgcn_global_load_lds((const __attribute__((address_space(1))) u32*)g,
                                   (__attribute__((address_space(3))) u32*)l, 16, 0, 0);
}

// ---------------- weight cast fp32 -> bf16 ----------------
__global__ __launch_bounds__(256) void castw(const float* __restrict__ src,
                                             u16* __restrict__ dst, int n4) {
  int i = blockIdx.x * 256 + threadIdx.x;
  if (i < n4) {
    float4 v = ((const float4*)src)[i];
    u16x4 r;
    r.x = f2bf(v.x); r.y = f2bf(v.y); r.z = f2bf(v.z); r.w = f2bf(v.w);
    ((u16x4*)dst)[i] = r;
  }
}

// ---------------- RMSNorm: fp32 [rows,1024] -> bf16 ----------------
__global__ __launch_bounds__(256) void rmsnorm_k(const float* __restrict__ x,
                                                 const float* __restrict__ gamma,
                                                 u16* __restrict__ o) {
  const int row = blockIdx.x;
  const int t = threadIdx.x;
  float4 v = ((const float4*)(x + (size_t)row * 1024))[t];
  float ss = v.x * v.x + v.y * v.y + v.z * v.z + v.w * v.w;
  #pragma unroll
  for (int m = 1; m < 64; m <<= 1) ss += __shfl_xor(ss, m);
  __shared__ float wsum[4];
  if ((t & 63) == 0) wsum[t >> 6] = ss;
  __syncthreads();
  float tot = wsum[0] + wsum[1] + wsum[2] + wsum[3];
  float inv = rsqrtf(tot * (1.0f / 1024.0f) + 1e-5f);
  float4 g = ((const float4*)gamma)[t];
  u16x4 r;
  r.x = f2bf(v.x * inv * g.x);
  r.y = f2bf(v.y * inv * g.y);
  r.z = f2bf(v.z * inv * g.z);
  r.w = f2bf(v.w * inv * g.w);
  ((u16x4*)(o + (size_t)row * 1024))[t] = r;
}

// ---------------- GEMM: C[M,N] = A[M,K] * B[N,K]^T (bf16 in, fp32 acc) ----
template <int EPI>
__global__ __launch_bounds__(256, 2)
void gemm_bt(const u16* __restrict__ A, const u16* __restrict__ B,
             void* out, const void* ep, int M, int N, int K, float scale) {
  __shared__ u16 As[128 * 32];
  __shared__ u16 Bs[128 * 32];
  const int tid = threadIdx.x;
  const int lane = tid & 63;
  const int w = tid >> 6;
  const int wr = w >> 1, wc = w & 1;
  // XCD-aware bijective swizzle (grids here always have nwg % 8 == 0)
  const int nx = gridDim.x;
  const int nwg = nx * gridDim.y;
  const int flat = blockIdx.y * nx + blockIdx.x;
  const int swz = (flat & 7) * (nwg >> 3) + (flat >> 3);
  const int m0 = (swz / nx) * 128;
  const int n0 = (swz % nx) * 128;
  const int lr = lane & 15;
  const int lk = lane >> 4;
  const int srow = lane >> 2;
  const int scol = (lane & 3) * 8;

  const f32x4 zero4 = {0.f, 0.f, 0.f, 0.f};
  f32x4 acc[4][4];
  #pragma unroll
  for (int i = 0; i < 4; i++)
    #pragma unroll
    for (int j = 0; j < 4; j++) acc[i][j] = zero4;

  for (int kt = 0; kt < K; kt += 32) {
    __syncthreads();
    #pragma unroll
    for (int c = 0; c < 2; c++) {
      const int rbase = w * 32 + c * 16;
      gload_lds16(A + (size_t)(m0 + rbase + srow) * K + kt + scol, &As[rbase * 32]);
      gload_lds16(B + (size_t)(n0 + rbase + srow) * K + kt + scol, &Bs[rbase * 32]);
    }
    __syncthreads();
    bf16x8 af[4], bfr[4];
    #pragma unroll
    for (int i = 0; i < 4; i++)
      af[i] = *(const bf16x8*)&As[(wr * 64 + i * 16 + lr) * 32 + lk * 8];
    #pragma unroll
    for (int j = 0; j < 4; j++)
      bfr[j] = *(const bf16x8*)&Bs[(wc * 64 + j * 16 + lr) * 32 + lk * 8];
    #pragma unroll
    for (int i = 0; i < 4; i++)
      #pragma unroll
      for (int j = 0; j < 4; j++)
        acc[i][j] = __builtin_amdgcn_mfma_f32_16x16x32_bf16(af[i], bfr[j], acc[i][j], 0, 0, 0);
  }

  const int r0 = lk * 4;
  #pragma unroll
  for (int i = 0; i < 4; i++) {
    #pragma unroll
    for (int j = 0; j < 4; j++) {
      #pragma unroll
      for (int r = 0; r < 4; r++) {
        const int grow = m0 + wr * 64 + i * 16 + r0 + r;
        const int gcol = n0 + wc * 64 + j * 16 + lr;
        const size_t idx = (size_t)grow * N + gcol;
        const float val = acc[i][j][r];
        if (EPI == 0) {
          ((u16*)out)[idx] = f2bf(val * scale);
        } else if (EPI == 1) {
          ((float*)out)[idx] = ((const float*)ep)[idx] + val;
        } else {
          float gv = bf2f(((const u16*)ep)[idx]);
          float sg = gv / (1.f + __expf(-gv));
          ((u16*)out)[idx] = f2bf(sg * val);
        }
      }
    }
  }
}

// ---------------- V transpose: vb[8192][1024] -> vt[bh=64][d=64][s=2048] ----
__global__ __launch_bounds__(256) void vtrans(const u16* __restrict__ vb,
                                              u16* __restrict__ vt) {
  __shared__ u16 T[64][72];
  const int t = threadIdx.x;
  const int s0 = blockIdx.x * 64;
  const int h = blockIdx.y;         // 16 tiles of 64 cols = one head each
  const int b = blockIdx.z;
  const int sl = t >> 2, dl = (t & 3) * 16;
  const u16* src = vb + ((size_t)(b * 2048 + s0 + sl)) * 1024 + h * 64 + dl;
  bf16x8 v0 = *(const bf16x8*)src;
  bf16x8 v1 = *(const bf16x8*)(src + 8);
  #pragma unroll
  for (int j = 0; j < 8; j++) T[dl + j][sl] = (u16)v0[j];
  #pragma unroll
  for (int j = 0; j < 8; j++) T[dl + 8 + j][sl] = (u16)v1[j];
  __syncthreads();
  const int dl2 = t >> 2, sl2 = (t & 3) * 16;
  u16* dst = vt + ((size_t)((b * 16 + h) * 64 + dl2)) * 2048 + s0 + sl2;
  *(bf16x8*)dst = *(const bf16x8*)&T[dl2][sl2];
  *(bf16x8*)(dst + 8) = *(const bf16x8*)&T[dl2][sl2 + 8];
}

// ---------------- causal flash attention v2 ----------------
// q,k,o: bf16 [8192][1024] (q pre-scaled by 1/8); vt: bf16 [64][64][2048].
// grid (16 qtiles, 64 bh), 256 threads = 4 waves; wave w owns q rows
// [qbase + w*32, +32). Swapped QK^T (32x32x16) keeps softmax lane-local.
__global__ __launch_bounds__(256)
void attn_fwd2(const u16* __restrict__ q, const u16* __restrict__ k,
               const u16* __restrict__ vt, u16* __restrict__ o) {
  __shared__ u16 sm[9216];           // K tile 4096 | VT tile 4096 ; Ot reuses
  u16* const smK = sm;
  u16* const smV = sm + 4096;

  const int tid = threadIdx.x;
  const int lane = tid & 63;
  const int w = tid >> 6;
  const int hi = lane >> 5;
  const int ln = lane & 31;

  // XCD swizzle: consecutive swz share bh -> K/V panel locality per XCD
  const int flat = blockIdx.y * 16 + blockIdx.x;
  const int swz = (flat & 7) * 128 + (flat >> 3);
  const int qt = swz & 15;
  const int bh = swz >> 4;
  const int b = bh >> 4, h = bh & 15;

  const int qbase = qt * 128;
  const int qw0 = qbase + w * 32;
  const int qglob = qw0 + ln;
  const int nkb = qt * 2 + 2;

  // Q fragments: lane holds Q[qw0+ln][c*16 + hi*8 + j]
  bf16x8 qf[4];
  {
    const u16* qp = q + ((size_t)(b * 2048 + qw0 + ln)) * 1024 + h * 64 + hi * 8;
    #pragma unroll
    for (int c = 0; c < 4; c++) qf[c] = *(const bf16x8*)(qp + c * 16);
  }

  f32x16 accO[2];
  #pragma unroll
  for (int i = 0; i < 2; i++)
    #pragma unroll
    for (int r = 0; r < 16; r++) accO[i][r] = 0.f;
  float mrun = -1e30f, lsum = 0.f;

  for (int kb = 0; kb < nkb; kb++) {
    const int kbase = kb * 64;
    __syncthreads();
    // stage K[64 keys][64 d] and VT[64 d][64 s] with XOR-swizzled sources
    #pragma unroll
    for (int r = 0; r < 2; r++) {
      const int cb = w * 128 + r * 64;
      const int ci = cb + lane;
      {
        const int key = ci >> 3, gch = (ci & 7) ^ (key & 7);
        const u16* src = k + ((size_t)(b * 2048 + kbase + key)) * 1024 + h * 64 + gch * 8;
        gload_lds16(src, (char*)smK + cb * 16);
      }
      {
        const int d = ci >> 3, gch = (ci & 7) ^ (d & 7);
        const u16* src = vt + ((size_t)(bh * 64 + d)) * 2048 + kbase + gch * 8;
        gload_lds16(src, (char*)smV + cb * 16);
      }
    }
    __syncthreads();

    if (kbase <= qw0 + 31) {
      // S^T[k][q] = sum_d K[k][d] Q[q][d]
      f32x16 st[2];
      #pragma unroll
      for (int kt = 0; kt < 2; kt++) {
        #pragma unroll
        for (int r = 0; r < 16; r++) st[kt][r] = 0.f;
        #pragma unroll
        for (int c = 0; c < 4; c++) {
          const int row = kt * 32 + ln;
          const int sch = (c * 2 + hi) ^ (ln & 7);
          bf16x8 kf = *(const bf16x8*)((const char*)smK + row * 128 + sch * 16);
          st[kt] = __builtin_amdgcn_mfma_f32_32x32x16_bf16(kf, qf[c], st[kt], 0, 0, 0);
        }
      }
      // causal mask (only diagonal tiles)
      if (kbase + 63 > qw0) {
        #pragma unroll
        for (int kt = 0; kt < 2; kt++)
          #pragma unroll
          for (int r = 0; r < 16; r++) {
            const int kk = kbase + kt * 32 + (r & 3) + 8 * (r >> 2) + 4 * hi;
            if (kk > qglob) st[kt][r] = -1e30f;
          }
      }
      // online softmax: lane owns q = qw0+ln (rows split with lane^32)
      float pm = st[0][0];
      #pragma unroll
      for (int kt = 0; kt < 2; kt++)
        #pragma unroll
        for (int r = 0; r < 16; r++) pm = fmaxf(pm, st[kt][r]);
      pm = fmaxf(pm, __shfl_xor(pm, 32));
      const float mnew = fmaxf(mrun, pm);
      const float alpha = __expf(mrun - mnew);
      float ps = 0.f;
      #pragma unroll
      for (int kt = 0; kt < 2; kt++)
        #pragma unroll
        for (int r = 0; r < 16; r++) {
          const float p = __expf(st[kt][r] - mnew);
          st[kt][r] = p;
          ps += p;
        }
      ps += __shfl_xor(ps, 32);
      lsum = lsum * alpha + ps;
      mrun = mnew;
      accO[0] *= alpha;
      accO[1] *= alpha;

      // P fragments + O^T[d][q] += V^T P
      #pragma unroll
      for (int kt = 0; kt < 2; kt++) {
        u32 pw[8], px[8];
        #pragma unroll
        for (int i = 0; i < 8; i++) pw[i] = pack2(st[kt][2 * i], st[kt][2 * i + 1]);
        #pragma unroll
        for (int i = 0; i < 8; i++) px[i] = (u32)__shfl_xor((int)pw[i], 32);
        union { u32 wd[4]; bf16x8 v; } f0, f1;
        f0.wd[0] = hi ? px[2] : pw[0];
        f0.wd[1] = hi ? px[3] : pw[1];
        f0.wd[2] = hi ? pw[2] : px[0];
        f0.wd[3] = hi ? pw[3] : px[1];
        f1.wd[0] = hi ? px[6] : pw[4];
        f1.wd[1] = hi ? px[7] : pw[5];
        f1.wd[2] = hi ? pw[6] : px[4];
        f1.wd[3] = hi ? pw[7] : px[5];
        #pragma unroll
        for (int d0 = 0; d0 < 2; d0++) {
          #pragma unroll
          for (int kc = 0; kc < 2; kc++) {
            const int drow = d0 * 32 + ln;
            const int sch = (kt * 4 + kc * 2 + hi) ^ (ln & 7);
            bf16x8 vf = *(const bf16x8*)((const char*)smV + drow * 128 + sch * 16);
            accO[d0] = __builtin_amdgcn_mfma_f32_32x32x16_bf16(vf, kc ? f1.v : f0.v,
                                                               accO[d0], 0, 0, 0);
          }
        }
      }
    }
  }

  __syncthreads();
  // O^T -> LDS bounce [128 q][72 d-pad], then coalesced global store
  const float inv = 1.0f / lsum;
  #pragma unroll
  for (int d0 = 0; d0 < 2; d0++)
    #pragma unroll
    for (int r = 0; r < 16; r++) {
      const int d = d0 * 32 + (r & 3) + 8 * (r >> 2) + 4 * hi;
      sm[(w * 32 + ln) * 72 + d] = f2bf(accO[d0][r] * inv);
    }
  __syncthreads();
  const int ql = tid >> 1, dh = (tid & 1) * 32;
  const u16* srcp = &sm[ql * 72 + dh];
  u16* dst = o + ((size_t)(b * 2048 + qbase + ql)) * 1024 + h * 64 + dh;
  #pragma unroll
  for (int j = 0; j < 4; j++)
    *(bf16x8*)(dst + j * 8) = *(const bf16x8*)(srcp + j * 8);
}

// ---------------- host ----------------
extern "C" void kernel_launch(void* const* d_in, const int* in_sizes, int n_in,
                              void* d_out, int out_size, void* d_ws, size_t ws_size,
                              hipStream_t stream) {
  const float* x      = (const float*)d_in[0];
  const float* W_q    = (const float*)d_in[1];
  const float* W_k    = (const float*)d_in[2];
  const float* W_v    = (const float*)d_in[3];
  const float* W_o    = (const float*)d_in[4];
  const float* gamma1 = (const float*)d_in[5];
  const float* gamma2 = (const float*)d_in[6];
  const float* W1     = (const float*)d_in[7];
  const float* W2     = (const float*)d_in[8];
  const float* W3     = (const float*)d_in[9];

  char* ws = (char*)d_ws;
  const size_t MB = 1ull << 20;
  u16* Wq_b  = (u16*)(ws + 0 * MB);
  u16* Wk_b  = (u16*)(ws + 2 * MB);
  u16* Wv_b  = (u16*)(ws + 4 * MB);
  u16* Wo_b  = (u16*)(ws + 6 * MB);
  u16* W1_b  = (u16*)(ws + 8 * MB);
  u16* W3_b  = (u16*)(ws + 16 * MB);
  u16* W2_b  = (u16*)(ws + 24 * MB);
  u16* xn    = (u16*)(ws + 32 * MB);
  u16* qb    = (u16*)(ws + 48 * MB);
  u16* kb    = (u16*)(ws + 64 * MB);
  u16* vb    = (u16*)(ws + 80 * MB);
  u16* attnb = (u16*)(ws + 96 * MB);
  u16* vtb   = (u16*)(ws + 112 * MB);  // 16 MB, dead after attn (gbuf reuses)
  u16* gbuf  = (u16*)(ws + 112 * MB);
  u16* hbuf  = (u16*)(ws + 48 * MB);
  float* x1  = (float*)d_out;

  castw<<<1024, 256, 0, stream>>>(W_q, Wq_b, 262144);
  castw<<<1024, 256, 0, stream>>>(W_k, Wk_b, 262144);
  castw<<<1024, 256, 0, stream>>>(W_v, Wv_b, 262144);
  castw<<<1024, 256, 0, stream>>>(W_o, Wo_b, 262144);
  castw<<<4096, 256, 0, stream>>>(W1, W1_b, 1048576);
  castw<<<4096, 256, 0, stream>>>(W3, W3_b, 1048576);
  castw<<<4096, 256, 0, stream>>>(W2, W2_b, 1048576);

  rmsnorm_k<<<8192, 256, 0, stream>>>(x, gamma1, xn);
  gemm_bt<0><<<dim3(8, 64), 256, 0, stream>>>(xn, Wq_b, qb, nullptr, 8192, 1024, 1024, 0.125f);
  gemm_bt<0><<<dim3(8, 64), 256, 0, stream>>>(xn, Wk_b, kb, nullptr, 8192, 1024, 1024, 1.0f);
  gemm_bt<0><<<dim3(8, 64), 256, 0, stream>>>(xn, Wv_b, vb, nullptr, 8192, 1024, 1024, 1.0f);
  vtrans<<<dim3(32, 16, 4), 256, 0, stream>>>(vb, vtb);
  attn_fwd2<<<dim3(16, 64), 256, 0, stream>>>(qb, kb, vtb, attnb);
  gemm_bt<1><<<dim3(8, 64), 256, 0, stream>>>(attnb, Wo_b, x1, x, 8192, 1024, 1024, 1.0f);

  rmsnorm_k<<<8192, 256, 0, stream>>>(x1, gamma2, xn);
  gemm_bt<0><<<dim3(32, 64), 256, 0, stream>>>(xn, W1_b, gbuf, nullptr, 8192, 4096, 1024, 1.0f);
  gemm_bt<2><<<dim3(32, 64), 256, 0, stream>>>(xn, W3_b, hbuf, gbuf, 8192, 4096, 1024, 1.0f);
  gemm_bt<1><<<dim3(8, 64), 256, 0, stream>>>(hbuf, W2_b, (float*)d_out, x1, 8192, 1024, 4096, 1.0f);
}

// Round 3
// 562.093 us; speedup vs baseline: 1.6004x; 1.0308x over previous
//
#include <hip/hip_runtime.h>
#include <cstdint>
#include <cstddef>

typedef unsigned short u16;
typedef unsigned int u32;
typedef short bf16x8 __attribute__((ext_vector_type(8)));
typedef float f32x4 __attribute__((ext_vector_type(4)));
typedef float f32x16 __attribute__((ext_vector_type(16)));
typedef u16 u16x4 __attribute__((ext_vector_type(4)));

__device__ __forceinline__ u16 f2bf(float f) {
  u32 u = __float_as_uint(f);
  return (u16)((u + 0x7FFFu + ((u >> 16) & 1u)) >> 16);
}
__device__ __forceinline__ float bf2f(u16 h) {
  return __uint_as_float(((u32)h) << 16);
}
__device__ __forceinline__ u32 pack2(float a, float b) {
  return (u32)f2bf(a) | ((u32)f2bf(b) << 16);
}

__device__ __forceinline__ void gload_lds16(const void* g, void* l) {
  __builtin_amdgcn_global_load_lds((const __attribute__((address_space(1))) u32*)g,
                                   (__attribute__((address_space(3))) u32*)l, 16, 0, 0);
}

#define BAR() asm volatile("s_barrier" ::: "memory")

// ---------------- weight cast fp32 -> bf16 ----------------
__global__ __launch_bounds__(256) void castw(const float* __restrict__ src,
                                             u16* __restrict__ dst, int n4) {
  int i = blockIdx.x * 256 + threadIdx.x;
  if (i < n4) {
    float4 v = ((const float4*)src)[i];
    u16x4 r;
    r.x = f2bf(v.x); r.y = f2bf(v.y); r.z = f2bf(v.z); r.w = f2bf(v.w);
    ((u16x4*)dst)[i] = r;
  }
}

// ---------------- RMSNorm: fp32 [rows,1024] -> bf16 ----------------
__global__ __launch_bounds__(256) void rmsnorm_k(const float* __restrict__ x,
                                                 const float* __restrict__ gamma,
                                                 u16* __restrict__ o) {
  const int row = blockIdx.x;
  const int t = threadIdx.x;
  float4 v = ((const float4*)(x + (size_t)row * 1024))[t];
  float ss = v.x * v.x + v.y * v.y + v.z * v.z + v.w * v.w;
  #pragma unroll
  for (int m = 1; m < 64; m <<= 1) ss += __shfl_xor(ss, m);
  __shared__ float wsum[4];
  if ((t & 63) == 0) wsum[t >> 6] = ss;
  __syncthreads();
  float tot = wsum[0] + wsum[1] + wsum[2] + wsum[3];
  float inv = rsqrtf(tot * (1.0f / 1024.0f) + 1e-5f);
  float4 g = ((const float4*)gamma)[t];
  u16x4 r;
  r.x = f2bf(v.x * inv * g.x);
  r.y = f2bf(v.y * inv * g.y);
  r.z = f2bf(v.z * inv * g.z);
  r.w = f2bf(v.w * inv * g.w);
  ((u16x4*)(o + (size_t)row * 1024))[t] = r;
}

// ========== 256x256 8-phase GEMM: C[M,N] = A[M,K] * B[N,K]^T ==========
// 512 threads = 8 waves (2M x 4N), per-wave 128x64 output, BK=64,
// double-buffered 128KiB LDS, T2 chunk-XOR swizzle, counted vmcnt(8),
// setprio around MFMA clusters.  EPI 0: bf16 = acc * (col<ncut?scale:1)
// EPI 2: bf16 = silu(ep[idx]) * acc
template <int EPI>
__global__ __launch_bounds__(512, 2)
void gemm256(const u16* __restrict__ A, const u16* __restrict__ B,
             void* out, const void* ep, int M, int N, int K,
             float scale, int ncut) {
  __shared__ u16 smA[2][16384];   // [buf][256 rows x 64]
  __shared__ u16 smB[2][16384];

  const int tid = threadIdx.x;
  const int lane = tid & 63;
  const int w = tid >> 6;
  const int wm = w >> 2, wn = w & 3;
  const int lr = lane & 15, lk = lane >> 4;

  // bijective XCD swizzle (m204)
  const int nx = gridDim.x;
  const int nwg = nx * gridDim.y;
  const int flat = blockIdx.y * nx + blockIdx.x;
  const int qq = nwg >> 3, rr = nwg & 7;
  const int xcd = flat & 7, off = flat >> 3;
  const int swz = (xcd < rr ? xcd * (qq + 1) : rr * (qq + 1) + (xcd - rr) * qq) + off;
  const int m0 = (swz / nx) * 256;
  const int n0 = (swz % nx) * 256;

  // staging geometry: one block-wide gload covers 64 rows (8KB)
  const int srow = w * 8 + (lane >> 3);              // 0..63 within quarter
  const int sch8 = (((lane & 7) ^ ((lane >> 3) & 7)) << 3);

  // read geometry
  const int rA = wm * 128 + lr;
  const int rB = wn * 64 + lr;
  const int kc0 = (lk ^ (lr & 7)) << 4;              // byte offset of ks=0 chunk
  const int kc1 = kc0 ^ 64;                          // ks=1 chunk

  const char* ldsA = (const char*)smA;
  const char* ldsB = (const char*)smB;

  const int NT = K >> 6;

  #define STAGE_A(q, U) gload_lds16(A + (size_t)(m0 + (q) * 64 + srow) * K + ((U) << 6) + sch8, \
                                    (char*)smA + (((U) & 1) << 15) + (q) * 8192 + w * 1024)
  #define STAGE_B(q, U) gload_lds16(B + (size_t)(n0 + (q) * 64 + srow) * K + ((U) << 6) + sch8, \
                                    (char*)smB + (((U) & 1) << 15) + (q) * 8192 + w * 1024)

  // prologue: stage tiles 0 and 1
  #pragma unroll
  for (int q = 0; q < 4; q++) STAGE_A(q, 0);
  #pragma unroll
  for (int q = 0; q < 4; q++) STAGE_B(q, 0);
  #pragma unroll
  for (int q = 0; q < 4; q++) STAGE_A(q, 1);
  #pragma unroll
  for (int q = 0; q < 4; q++) STAGE_B(q, 1);
  asm volatile("s_waitcnt vmcnt(8)" ::: "memory");
  BAR();

  f32x4 acc[8][4];
  #pragma unroll
  for (int i = 0; i < 8; i++)
    #pragma unroll
    for (int j = 0; j < 4; j++) acc[i][j] = (f32x4){0.f, 0.f, 0.f, 0.f};

  bf16x8 af[4][2], bfa[2][2], bfb[2][2];

  for (int W = 0; W < NT; ++W) {
    const int b = W & 1;
    const bool st = (W + 2 < NT);
    const int U = st ? (W + 2) : 0;
    const char* pA = ldsA + (b << 15) + rA * 128;
    const char* pB = ldsB + (b << 15) + rB * 128;

    // ---- P0: read A(ih0) + B(jh0); MFMA quad (ih0,jh0)
    #pragma unroll
    for (int i = 0; i < 4; i++) {
      af[i][0] = *(const bf16x8*)(pA + i * 2048 + kc0);
      af[i][1] = *(const bf16x8*)(pA + i * 2048 + kc1);
    }
    #pragma unroll
    for (int j = 0; j < 2; j++) {
      bfa[j][0] = *(const bf16x8*)(pB + j * 2048 + kc0);
      bfa[j][1] = *(const bf16x8*)(pB + j * 2048 + kc1);
    }
    BAR();
    __builtin_amdgcn_s_setprio(1);
    #pragma unroll
    for (int i = 0; i < 4; i++)
      #pragma unroll
      for (int j = 0; j < 2; j++) {
        acc[i][j] = __builtin_amdgcn_mfma_f32_16x16x32_bf16(af[i][0], bfa[j][0], acc[i][j], 0, 0, 0);
        acc[i][j] = __builtin_amdgcn_mfma_f32_16x16x32_bf16(af[i][1], bfa[j][1], acc[i][j], 0, 0, 0);
      }
    __builtin_amdgcn_s_setprio(0);
    BAR();

    // ---- P1: read B(jh1); stage A(W+2) q0,q2; MFMA (ih0,jh1)
    #pragma unroll
    for (int j = 0; j < 2; j++) {
      bfb[j][0] = *(const bf16x8*)(pB + (j + 2) * 2048 + kc0);
      bfb[j][1] = *(const bf16x8*)(pB + (j + 2) * 2048 + kc1);
    }
    if (st) { STAGE_A(0, U); STAGE_A(2, U); }
    BAR();
    __builtin_amdgcn_s_setprio(1);
    #pragma unroll
    for (int i = 0; i < 4; i++)
      #pragma unroll
      for (int j = 0; j < 2; j++) {
        acc[i][j + 2] = __builtin_amdgcn_mfma_f32_16x16x32_bf16(af[i][0], bfb[j][0], acc[i][j + 2], 0, 0, 0);
        acc[i][j + 2] = __builtin_amdgcn_mfma_f32_16x16x32_bf16(af[i][1], bfb[j][1], acc[i][j + 2], 0, 0, 0);
      }
    __builtin_amdgcn_s_setprio(0);
    BAR();

    // ---- P2: read A(ih1); stage B(W+2) q0..q3; MFMA (ih1,jh0)
    #pragma unroll
    for (int i = 0; i < 4; i++) {
      af[i][0] = *(const bf16x8*)(pA + (i + 4) * 2048 + kc0);
      af[i][1] = *(const bf16x8*)(pA + (i + 4) * 2048 + kc1);
    }
    if (st) { STAGE_B(0, U); STAGE_B(1, U); STAGE_B(2, U); STAGE_B(3, U); }
    BAR();
    __builtin_amdgcn_s_setprio(1);
    #pragma unroll
    for (int i = 0; i < 4; i++)
      #pragma unroll
      for (int j = 0; j < 2; j++) {
        acc[i + 4][j] = __builtin_amdgcn_mfma_f32_16x16x32_bf16(af[i][0], bfa[j][0], acc[i + 4][j], 0, 0, 0);
        acc[i + 4][j] = __builtin_amdgcn_mfma_f32_16x16x32_bf16(af[i][1], bfa[j][1], acc[i + 4][j], 0, 0, 0);
      }
    __builtin_amdgcn_s_setprio(0);
    BAR();

    // ---- P3: stage A(W+2) q1,q3; MFMA (ih1,jh1); boundary vmcnt
    if (st) { STAGE_A(1, U); STAGE_A(3, U); }
    BAR();
    __builtin_amdgcn_s_setprio(1);
    #pragma unroll
    for (int i = 0; i < 4; i++)
      #pragma unroll
      for (int j = 0; j < 2; j++) {
        acc[i + 4][j + 2] = __builtin_amdgcn_mfma_f32_16x16x32_bf16(af[i][0], bfb[j][0], acc[i + 4][j + 2], 0, 0, 0);
        acc[i + 4][j + 2] = __builtin_amdgcn_mfma_f32_16x16x32_bf16(af[i][1], bfb[j][1], acc[i + 4][j + 2], 0, 0, 0);
      }
    __builtin_amdgcn_s_setprio(0);
    if (st) asm volatile("s_waitcnt vmcnt(8)" ::: "memory");
    else    asm volatile("s_waitcnt vmcnt(0)" ::: "memory");
    BAR();
  }

  #undef STAGE_A
  #undef STAGE_B

  // epilogue
  #pragma unroll
  for (int i = 0; i < 8; i++)
    #pragma unroll
    for (int j = 0; j < 4; j++)
      #pragma unroll
      for (int r = 0; r < 4; r++) {
        const int grow = m0 + wm * 128 + i * 16 + lk * 4 + r;
        const int gcol = n0 + wn * 64 + j * 16 + lr;
        const size_t idx = (size_t)grow * N + gcol;
        const float val = acc[i][j][r];
        if (EPI == 0) {
          const float s = (gcol < ncut) ? scale : 1.0f;
          ((u16*)out)[idx] = f2bf(val * s);
        } else {
          float gv = bf2f(((const u16*)ep)[idx]);
          float sg = gv / (1.f + __expf(-gv));
          ((u16*)out)[idx] = f2bf(sg * val);
        }
      }
}

// ---------------- legacy 128x128 GEMM (N=1024 cases) ----------------
// EPI 1: out fp32 = acc + ep_fp32[idx]
template <int EPI>
__global__ __launch_bounds__(256, 2)
void gemm_bt(const u16* __restrict__ A, const u16* __restrict__ B,
             void* out, const void* ep, int M, int N, int K, float scale) {
  __shared__ u16 As[128 * 32];
  __shared__ u16 Bs[128 * 32];
  const int tid = threadIdx.x;
  const int lane = tid & 63;
  const int w = tid >> 6;
  const int wr = w >> 1, wc = w & 1;
  const int nx = gridDim.x;
  const int nwg = nx * gridDim.y;
  const int flat = blockIdx.y * nx + blockIdx.x;
  const int swz = (flat & 7) * (nwg >> 3) + (flat >> 3);
  const int m0 = (swz / nx) * 128;
  const int n0 = (swz % nx) * 128;
  const int lr = lane & 15;
  const int lk = lane >> 4;
  const int srow = lane >> 2;
  const int scol = (lane & 3) * 8;

  const f32x4 zero4 = {0.f, 0.f, 0.f, 0.f};
  f32x4 acc[4][4];
  #pragma unroll
  for (int i = 0; i < 4; i++)
    #pragma unroll
    for (int j = 0; j < 4; j++) acc[i][j] = zero4;

  for (int kt = 0; kt < K; kt += 32) {
    __syncthreads();
    #pragma unroll
    for (int c = 0; c < 2; c++) {
      const int rbase = w * 32 + c * 16;
      gload_lds16(A + (size_t)(m0 + rbase + srow) * K + kt + scol, &As[rbase * 32]);
      gload_lds16(B + (size_t)(n0 + rbase + srow) * K + kt + scol, &Bs[rbase * 32]);
    }
    __syncthreads();
    bf16x8 af[4], bfr[4];
    #pragma unroll
    for (int i = 0; i < 4; i++)
      af[i] = *(const bf16x8*)&As[(wr * 64 + i * 16 + lr) * 32 + lk * 8];
    #pragma unroll
    for (int j = 0; j < 4; j++)
      bfr[j] = *(const bf16x8*)&Bs[(wc * 64 + j * 16 + lr) * 32 + lk * 8];
    #pragma unroll
    for (int i = 0; i < 4; i++)
      #pragma unroll
      for (int j = 0; j < 4; j++)
        acc[i][j] = __builtin_amdgcn_mfma_f32_16x16x32_bf16(af[i], bfr[j], acc[i][j], 0, 0, 0);
  }

  const int r0 = lk * 4;
  #pragma unroll
  for (int i = 0; i < 4; i++) {
    #pragma unroll
    for (int j = 0; j < 4; j++) {
      #pragma unroll
      for (int r = 0; r < 4; r++) {
        const int grow = m0 + wr * 64 + i * 16 + r0 + r;
        const int gcol = n0 + wc * 64 + j * 16 + lr;
        const size_t idx = (size_t)grow * N + gcol;
        const float val = acc[i][j][r];
        if (EPI == 0) {
          ((u16*)out)[idx] = f2bf(val * scale);
        } else if (EPI == 1) {
          ((float*)out)[idx] = ((const float*)ep)[idx] + val;
        } else {
          float gv = bf2f(((const u16*)ep)[idx]);
          float sg = gv / (1.f + __expf(-gv));
          ((u16*)out)[idx] = f2bf(sg * val);
        }
      }
    }
  }
}

// ---------------- V transpose from packed qkv: -> vt[bh=64][d=64][s=2048] ----
__global__ __launch_bounds__(256) void vtrans(const u16* __restrict__ qkv,
                                              u16* __restrict__ vt) {
  __shared__ u16 T[64][72];
  const int t = threadIdx.x;
  const int s0 = blockIdx.x * 64;
  const int h = blockIdx.y;
  const int b = blockIdx.z;
  const int sl = t >> 2, dl = (t & 3) * 16;
  const u16* src = qkv + ((size_t)(b * 2048 + s0 + sl)) * 3072 + 2048 + h * 64 + dl;
  bf16x8 v0 = *(const bf16x8*)src;
  bf16x8 v1 = *(const bf16x8*)(src + 8);
  #pragma unroll
  for (int j = 0; j < 8; j++) T[dl + j][sl] = (u16)v0[j];
  #pragma unroll
  for (int j = 0; j < 8; j++) T[dl + 8 + j][sl] = (u16)v1[j];
  __syncthreads();
  const int dl2 = t >> 2, sl2 = (t & 3) * 16;
  u16* dst = vt + ((size_t)((b * 16 + h) * 64 + dl2)) * 2048 + s0 + sl2;
  *(bf16x8*)dst = *(const bf16x8*)&T[dl2][sl2];
  *(bf16x8*)(dst + 8) = *(const bf16x8*)&T[dl2][sl2 + 8];
}

// ---------------- causal flash attention (packed qkv input) ----------------
__global__ __launch_bounds__(256)
void attn_fwd2(const u16* __restrict__ qkv, const u16* __restrict__ vt,
               u16* __restrict__ o) {
  __shared__ u16 sm[9216];
  u16* const smK = sm;
  u16* const smV = sm + 4096;

  const int tid = threadIdx.x;
  const int lane = tid & 63;
  const int w = tid >> 6;
  const int hi = lane >> 5;
  const int ln = lane & 31;

  const int flat = blockIdx.y * 16 + blockIdx.x;
  const int swz = (flat & 7) * 128 + (flat >> 3);
  const int qt = swz & 15;
  const int bh = swz >> 4;
  const int b = bh >> 4, h = bh & 15;

  const int qbase = qt * 128;
  const int qw0 = qbase + w * 32;
  const int qglob = qw0 + ln;
  const int nkb = qt * 2 + 2;

  bf16x8 qf[4];
  {
    const u16* qp = qkv + ((size_t)(b * 2048 + qw0 + ln)) * 3072 + h * 64 + hi * 8;
    #pragma unroll
    for (int c = 0; c < 4; c++) qf[c] = *(const bf16x8*)(qp + c * 16);
  }

  f32x16 accO[2];
  #pragma unroll
  for (int i = 0; i < 2; i++)
    #pragma unroll
    for (int r = 0; r < 16; r++) accO[i][r] = 0.f;
  float mrun = -1e30f, lsum = 0.f;

  for (int kb = 0; kb < nkb; kb++) {
    const int kbase = kb * 64;
    __syncthreads();
    #pragma unroll
    for (int r = 0; r < 2; r++) {
      const int cb = w * 128 + r * 64;
      const int ci = cb + lane;
      {
        const int key = ci >> 3, gch = (ci & 7) ^ (key & 7);
        const u16* src = qkv + ((size_t)(b * 2048 + kbase + key)) * 3072 + 1024 + h * 64 + gch * 8;
        gload_lds16(src, (char*)smK + cb * 16);
      }
      {
        const int d = ci >> 3, gch = (ci & 7) ^ (d & 7);
        const u16* src = vt + ((size_t)(bh * 64 + d)) * 2048 + kbase + gch * 8;
        gload_lds16(src, (char*)smV + cb * 16);
      }
    }
    __syncthreads();

    if (kbase <= qw0 + 31) {
      f32x16 st[2];
      #pragma unroll
      for (int kt = 0; kt < 2; kt++) {
        #pragma unroll
        for (int r = 0; r < 16; r++) st[kt][r] = 0.f;
        #pragma unroll
        for (int c = 0; c < 4; c++) {
          const int row = kt * 32 + ln;
          const int sch = (c * 2 + hi) ^ (ln & 7);
          bf16x8 kf = *(const bf16x8*)((const char*)smK + row * 128 + sch * 16);
          st[kt] = __builtin_amdgcn_mfma_f32_32x32x16_bf16(kf, qf[c], st[kt], 0, 0, 0);
        }
      }
      if (kbase + 63 > qw0) {
        #pragma unroll
        for (int kt = 0; kt < 2; kt++)
          #pragma unroll
          for (int r = 0; r < 16; r++) {
            const int kk = kbase + kt * 32 + (r & 3) + 8 * (r >> 2) + 4 * hi;
            if (kk > qglob) st[kt][r] = -1e30f;
          }
      }
      float pm = st[0][0];
      #pragma unroll
      for (int kt = 0; kt < 2; kt++)
        #pragma unroll
        for (int r = 0; r < 16; r++) pm = fmaxf(pm, st[kt][r]);
      pm = fmaxf(pm, __shfl_xor(pm, 32));
      const float mnew = fmaxf(mrun, pm);
      const float alpha = __expf(mrun - mnew);
      float ps = 0.f;
      #pragma unroll
      for (int kt = 0; kt < 2; kt++)
        #pragma unroll
        for (int r = 0; r < 16; r++) {
          const float p = __expf(st[kt][r] - mnew);
          st[kt][r] = p;
          ps += p;
        }
      ps += __shfl_xor(ps, 32);
      lsum = lsum * alpha + ps;
      mrun = mnew;
      accO[0] *= alpha;
      accO[1] *= alpha;

      #pragma unroll
      for (int kt = 0; kt < 2; kt++) {
        u32 pw[8], px[8];
        #pragma unroll
        for (int i = 0; i < 8; i++) pw[i] = pack2(st[kt][2 * i], st[kt][2 * i + 1]);
        #pragma unroll
        for (int i = 0; i < 8; i++) px[i] = (u32)__shfl_xor((int)pw[i], 32);
        union { u32 wd[4]; bf16x8 v; } f0, f1;
        f0.wd[0] = hi ? px[2] : pw[0];
        f0.wd[1] = hi ? px[3] : pw[1];
        f0.wd[2] = hi ? pw[2] : px[0];
        f0.wd[3] = hi ? pw[3] : px[1];
        f1.wd[0] = hi ? px[6] : pw[4];
        f1.wd[1] = hi ? px[7] : pw[5];
        f1.wd[2] = hi ? pw[6] : px[4];
        f1.wd[3] = hi ? pw[7] : px[5];
        #pragma unroll
        for (int d0 = 0; d0 < 2; d0++) {
          #pragma unroll
          for (int kc = 0; kc < 2; kc++) {
            const int drow = d0 * 32 + ln;
            const int sch = (kt * 4 + kc * 2 + hi) ^ (ln & 7);
            bf16x8 vf = *(const bf16x8*)((const char*)smV + drow * 128 + sch * 16);
            accO[d0] = __builtin_amdgcn_mfma_f32_32x32x16_bf16(vf, kc ? f1.v : f0.v,
                                                               accO[d0], 0, 0, 0);
          }
        }
      }
    }
  }

  __syncthreads();
  const float inv = 1.0f / lsum;
  #pragma unroll
  for (int d0 = 0; d0 < 2; d0++)
    #pragma unroll
    for (int r = 0; r < 16; r++) {
      const int d = d0 * 32 + (r & 3) + 8 * (r >> 2) + 4 * hi;
      sm[(w * 32 + ln) * 72 + d] = f2bf(accO[d0][r] * inv);
    }
  __syncthreads();
  const int ql = tid >> 1, dh = (tid & 1) * 32;
  const u16* srcp = &sm[ql * 72 + dh];
  u16* dst = o + ((size_t)(b * 2048 + qbase + ql)) * 1024 + h * 64 + dh;
  #pragma unroll
  for (int j = 0; j < 4; j++)
    *(bf16x8*)(dst + j * 8) = *(const bf16x8*)(srcp + j * 8);
}

// ---------------- host ----------------
extern "C" void kernel_launch(void* const* d_in, const int* in_sizes, int n_in,
                              void* d_out, int out_size, void* d_ws, size_t ws_size,
                              hipStream_t stream) {
  const float* x      = (const float*)d_in[0];
  const float* W_q    = (const float*)d_in[1];
  const float* W_k    = (const float*)d_in[2];
  const float* W_v    = (const float*)d_in[3];
  const float* W_o    = (const float*)d_in[4];
  const float* gamma1 = (const float*)d_in[5];
  const float* gamma2 = (const float*)d_in[6];
  const float* W1     = (const float*)d_in[7];
  const float* W2     = (const float*)d_in[8];
  const float* W3     = (const float*)d_in[9];

  char* ws = (char*)d_ws;
  const size_t MB = 1ull << 20;
  u16* qkvw  = (u16*)(ws + 0 * MB);    // Wq|Wk|Wv rows concat [3072][1024]
  u16* Wo_b  = (u16*)(ws + 6 * MB);
  u16* W1_b  = (u16*)(ws + 8 * MB);
  u16* W3_b  = (u16*)(ws + 16 * MB);
  u16* W2_b  = (u16*)(ws + 24 * MB);
  u16* xn    = (u16*)(ws + 32 * MB);   // 16 MB
  u16* qkvb  = (u16*)(ws + 48 * MB);   // [8192][3072] = 48 MB -> 48..96
  u16* attnb = (u16*)(ws + 96 * MB);   // 16 MB
  u16* vtb   = (u16*)(ws + 112 * MB);  // 16 MB (dead after attn)
  u16* gbuf  = (u16*)(ws + 112 * MB);  // 64 MB -> 112..176 (after attn)
  u16* hbuf  = (u16*)(ws + 48 * MB);   // 64 MB, reuses qkvb+attnb (dead)
  float* x1  = (float*)d_out;

  castw<<<1024, 256, 0, stream>>>(W_q, qkvw, 262144);
  castw<<<1024, 256, 0, stream>>>(W_k, qkvw + 1024 * 1024, 262144);
  castw<<<1024, 256, 0, stream>>>(W_v, qkvw + 2048 * 1024, 262144);
  castw<<<1024, 256, 0, stream>>>(W_o, Wo_b, 262144);
  castw<<<4096, 256, 0, stream>>>(W1, W1_b, 1048576);
  castw<<<4096, 256, 0, stream>>>(W3, W3_b, 1048576);
  castw<<<4096, 256, 0, stream>>>(W2, W2_b, 1048576);

  rmsnorm_k<<<8192, 256, 0, stream>>>(x, gamma1, xn);
  gemm256<0><<<dim3(12, 32), 512, 0, stream>>>(xn, qkvw, qkvb, nullptr,
                                               8192, 3072, 1024, 0.125f, 1024);
  vtrans<<<dim3(32, 16, 4), 256, 0, stream>>>(qkvb, vtb);
  attn_fwd2<<<dim3(16, 64), 256, 0, stream>>>(qkvb, vtb, attnb);
  gemm_bt<1><<<dim3(8, 64), 256, 0, stream>>>(attnb, Wo_b, x1, x, 8192, 1024, 1024, 1.0f);

  rmsnorm_k<<<8192, 256, 0, stream>>>(x1, gamma2, xn);
  gemm256<0><<<dim3(16, 32), 512, 0, stream>>>(xn, W1_b, gbuf, nullptr,
                                               8192, 4096, 1024, 1.0f, 0);
  gemm256<2><<<dim3(16, 32), 512, 0, stream>>>(xn, W3_b, hbuf, gbuf,
                                               8192, 4096, 1024, 1.0f, 0);
  gemm_bt<1><<<dim3(8, 64), 256, 0, stream>>>(hbuf, W2_b, (float*)d_out, x1,
                                              8192, 1024, 4096, 1.0f);
}